// Round 8
// baseline (1542.902 us; speedup 1.0000x reference)
//
#include <hip/hip_runtime.h>
#include <cstddef>
#include <cstdint>

#define NN 200000
#define NINT 25000   // nodes 0..24999 have children

typedef _Float16 f16;
typedef __attribute__((ext_vector_type(8))) f16 f16x8;
typedef __attribute__((ext_vector_type(4))) float f32x4;

#define MFMA16(a,b,c) __builtin_amdgcn_mfma_f32_16x16x32_f16((a),(b),(c),0,0,0)

union H4 { uint2 u; f16 f[4]; };
union F4 { float4 v; float f[4]; uint4 u; };

__device__ __forceinline__ float fsig(float v){ return __builtin_amdgcn_rcpf(1.f+__expf(-v)); }
__device__ __forceinline__ float ftanh(float v){ return 1.f-2.f*__builtin_amdgcn_rcpf(1.f+__expf(2.f*v)); }
// fp16 split-2: v = hi + lo/4096 + O(2^-22 |v|)
__device__ __forceinline__ void split2(float v, f16&h, f16&l){ h=(f16)v; l=(f16)((v-(float)h)*4096.f); }

// bijective XCD-chunking swizzle
__device__ __forceinline__ int xcd_swz(int bid, int nwg){
    int q = nwg >> 3, r = nwg & 7;
    int xcd = bid & 7, i = bid >> 3;
    return (xcd < r ? xcd*(q+1) : r*(q+1) + (xcd-r)*q) + i;
}

// ---------------------------------------------------------------------------
// weight [K=256][N] fp32 -> col-frag layout (n*32 + k/8)*8 + (k&7), hi/lo f16
// (per-column contiguous 512B: per-ch loads become base + ch*64B immediates)
// ---------------------------------------------------------------------------
__global__ void split_w_kernel(const float* __restrict__ src,
                               f16* __restrict__ dh, f16* __restrict__ dl, int N)
{
    int e = blockIdx.x*256 + threadIdx.x;
    if (e >= 256*N) return;
    int k = e / N, n = e - k*N;
    f16 hh, ll; split2(src[e], hh, ll);
    size_t o = ((size_t)n*32 + (k>>3))*8 + (k&7);
    dh[o]=hh; dl[o]=ll;
}

// ---------------------------------------------------------------------------
// ht[p] = sum of h over the 8 consecutive children of p
// ---------------------------------------------------------------------------
__global__ void ht_sum(const float* __restrict__ h, float* __restrict__ ht,
                       int ps, int pe)
{
    int idx = blockIdx.x*256 + threadIdx.x;
    int p = ps + (idx >> 6);
    if (p >= pe) return;
    int dq = (idx & 63) << 2;
    F4 s; s.v = (float4){0,0,0,0};
    int c0 = p*8 + 1;
#pragma unroll
    for (int j = 0; j < 8; ++j) {
        int child = c0 + j;
        if (child < NN) {
            F4 v; v.v = *(const float4*)(h + (size_t)child*256 + dq);
#pragma unroll
            for (int e = 0; e < 4; ++e) s.f[e] += v.f[e];
        }
    }
    *(float4*)(ht + (size_t)(p - ps)*256 + dq) = s.v;
}

// ---------------------------------------------------------------------------
// iou_ls<NPH>: LDS-staged 64-node-tile GEMM vs W_iou/U_iou + LSTM epilogue.
// NPH=1: childless nodes (B=x, K=256, fc=0). NPH=2: internal parents
// (phase0: x@W_iou, phase1: ht@U_iou; K=512; +fc).
// Block: 512 thr = 8 waves; wave owns 16 d-cols x 3 gates (cls in {0,1} for
// d 0..127 / 128..255). Acts staged fp32->split-f16 into XOR-swizzled LDS,
// double-buffered, async issue (T14); 1 barrier/phase.
// ---------------------------------------------------------------------------
template<int NPH>
__launch_bounds__(512, 2)
__global__ void iou_ls(const float* __restrict__ xsrc, const float* __restrict__ htsrc,
                       const f16* __restrict__ wih, const f16* __restrict__ wil,
                       const f16* __restrict__ uih, const f16* __restrict__ uil,
                       const float* __restrict__ b_iou, const float* __restrict__ fcR,
                       float* __restrict__ cW, float* __restrict__ hW,
                       int base, int pend, int ntiles, int nch)
{
    __shared__ f16 A[2][64][512];   // 128 KB: [buf][row][hi 0..255 | lo 256..511]

    const int work = xcd_swz(blockIdx.x, gridDim.x);
    const int chunk = work >> 1, cls = work & 1;
    const int tpc = (ntiles + nch - 1)/nch;
    const int t0 = chunk * tpc;
    const int T = min(ntiles - t0, tpc);
    if (T <= 0) return;

    const int t = threadIdx.x, lane = t & 63, wv = t >> 6;
    const int c15 = lane & 15, qq = lane >> 4;
    const float INV = 1.f/4096.f;
    const int dloc = cls*128 + wv*16;
    const int d0 = dloc + qq*4;

    const size_t wb = (size_t)(dloc + c15)*256 + qq*8;  // frag base within gate 0

    F4 bi, bo, bu;
    bi.v = *(const float4*)(b_iou + d0);
    bo.v = *(const float4*)(b_iou + 256 + d0);
    bu.v = *(const float4*)(b_iou + 512 + d0);

    F4 st[8];
    auto ISSUE = [&](int p){
        const int j  = (NPH==2) ? (p>>1) : p;
        const int ph = (NPH==2) ? (p&1) : 0;
#pragma unroll
        for (int r = 0; r < 8; ++r) {
            int nloc = (t0 + j)*64 + wv*8 + r;
            if (ph == 0) {
                int node = min(base + nloc, pend - 1);
                st[r].v = *(const float4*)(xsrc + (size_t)node*256 + lane*4);
            } else {
                nloc = min(nloc, pend - base - 1);
                st[r].v = *(const float4*)(htsrc + (size_t)nloc*256 + lane*4);
            }
        }
    };
    auto WRITE = [&](int buf){
#pragma unroll
        for (int r = 0; r < 8; ++r) {
            H4 hi, lo;
#pragma unroll
            for (int e = 0; e < 4; ++e) split2(st[r].f[e], hi.f[e], lo.f[e]);
            char* wp = (char*)&A[buf][wv*8 + r][0];
            const int uo = (((lane>>1) ^ (r&7)) << 4) + ((lane&1) << 3);
            *(uint2*)(wp + uo) = hi.u;
            *(uint2*)(wp + 512 + uo) = lo.u;
        }
    };

    f32x4 aH[4][3], aL[4][3];
    const int P = NPH * T;

    ISSUE(0); WRITE(0); __syncthreads();

    for (int p = 0; p < P; ++p) {
        const int buf = p & 1;
        const int j  = (NPH==2) ? (p>>1) : p;
        const int ph = (NPH==2) ? (p&1) : 0;
        if (p + 1 < P) ISSUE(p + 1);
        if (ph == 0) {
#pragma unroll
            for (int tt = 0; tt < 4; ++tt)
#pragma unroll
                for (int g = 0; g < 3; ++g) {
                    aH[tt][g] = (f32x4){0,0,0,0};
                    aL[tt][g] = (f32x4){0,0,0,0};
                }
        }
        const f16* w0h = ((ph == 0) ? wih : uih) + wb;
        const f16* w0l = ((ph == 0) ? wil : uil) + wb;
        const f16* w1h = w0h + 65536;  const f16* w1l = w0l + 65536;
        const f16* w2h = w0h + 131072; const f16* w2l = w0l + 131072;
        const char* rb = (const char*)&A[buf][c15][0];
#pragma unroll
        for (int ch = 0; ch < 8; ++ch) {
            f16x8 g0h = *(const f16x8*)(w0h + ch*32);
            f16x8 g1h = *(const f16x8*)(w1h + ch*32);
            f16x8 g2h = *(const f16x8*)(w2h + ch*32);
            f16x8 g0l = *(const f16x8*)(w0l + ch*32);
            f16x8 g1l = *(const f16x8*)(w1l + ch*32);
            f16x8 g2l = *(const f16x8*)(w2l + ch*32);
            const int u = (((qq + ch*4) ^ (c15 & 7)) << 4);
#pragma unroll
            for (int tt = 0; tt < 4; ++tt) {
                f16x8 bh = *(const f16x8*)(rb + tt*16384 + u);
                f16x8 bl = *(const f16x8*)(rb + tt*16384 + 512 + u);
                aH[tt][0] = MFMA16(g0h, bh, aH[tt][0]);
                aL[tt][0] = MFMA16(g0h, bl, aL[tt][0]);
                aL[tt][0] = MFMA16(g0l, bh, aL[tt][0]);
                aH[tt][1] = MFMA16(g1h, bh, aH[tt][1]);
                aL[tt][1] = MFMA16(g1h, bl, aL[tt][1]);
                aL[tt][1] = MFMA16(g1l, bh, aL[tt][1]);
                aH[tt][2] = MFMA16(g2h, bh, aH[tt][2]);
                aL[tt][2] = MFMA16(g2h, bl, aL[tt][2]);
                aL[tt][2] = MFMA16(g2l, bh, aL[tt][2]);
            }
        }
        if (ph == NPH - 1) {
#pragma unroll
            for (int tt = 0; tt < 4; ++tt) {
                const int node = base + (t0 + j)*64 + tt*16 + c15;
                if (node < pend) {
                    F4 fcv; fcv.v = (float4){0,0,0,0};
                    if (NPH == 2) fcv.v = *(const float4*)(fcR + (size_t)(node - base)*256 + d0);
                    F4 cn, hn;
#pragma unroll
                    for (int e = 0; e < 4; ++e) {
                        float ig = aH[tt][0][e] + aL[tt][0][e]*INV + bi.f[e];
                        float og = aH[tt][1][e] + aL[tt][1][e]*INV + bo.f[e];
                        float ug = aH[tt][2][e] + aL[tt][2][e]*INV + bu.f[e];
                        float cc = fsig(ig)*ftanh(ug) + fcv.f[e];
                        cn.f[e] = cc;
                        hn.f[e] = fsig(og)*ftanh(cc);
                    }
                    const size_t no = (size_t)node*256 + d0;
                    *(float4*)(cW + no) = cn.v;
                    *(float4*)(hW + no) = hn.v;
                }
            }
        }
        if (p + 1 < P) WRITE(buf ^ 1);
        __syncthreads();
    }
}

// ---------------------------------------------------------------------------
// f_ls<FM>: LDS-staged 64-node-tile GEMM vs a 256-col weight (K=256).
// Wave owns 32 cols (2 frags); block covers all 256 cols -> 1 block/tile.
//   FM=0: xf = x@W_f + b_f (nodes 0..NINT).
//   FM=1: child pass: f = sigm(h@U_f + xf[par]); fc[par] = shfl-sum f*c.
// ---------------------------------------------------------------------------
template<int FM>
__launch_bounds__(512, 2)
__global__ void f_ls(const float* __restrict__ asrc,
                     const f16* __restrict__ wh, const f16* __restrict__ wl,
                     const float* __restrict__ b_f,
                     const float* __restrict__ xfR, const float* __restrict__ cR,
                     float* __restrict__ outW,
                     int base, int cend, int pp, int ntiles, int nch)
{
    __shared__ f16 A[2][64][512];

    const int chunk = xcd_swz(blockIdx.x, gridDim.x);
    const int tpc = (ntiles + nch - 1)/nch;
    const int t0 = chunk * tpc;
    const int T = min(ntiles - t0, tpc);
    if (T <= 0) return;

    const int t = threadIdx.x, lane = t & 63, wv = t >> 6;
    const int c15 = lane & 15, qq = lane >> 4;
    const float INV = 1.f/4096.f;

    const size_t wb0 = (size_t)(wv*32 + c15)*256 + qq*8;
    const f16* p0h = wh + wb0;   const f16* p0l = wl + wb0;
    const f16* p1h = p0h + 4096; const f16* p1l = p0l + 4096;

    F4 st[8];
    auto ISSUE = [&](int j){
#pragma unroll
        for (int r = 0; r < 8; ++r) {
            int node = min(base + (t0 + j)*64 + wv*8 + r, cend - 1);
            st[r].v = *(const float4*)(asrc + (size_t)node*256 + lane*4);
        }
    };
    auto WRITE = [&](int buf){
#pragma unroll
        for (int r = 0; r < 8; ++r) {
            H4 hi, lo;
#pragma unroll
            for (int e = 0; e < 4; ++e) split2(st[r].f[e], hi.f[e], lo.f[e]);
            char* wp = (char*)&A[buf][wv*8 + r][0];
            const int uo = (((lane>>1) ^ (r&7)) << 4) + ((lane&1) << 3);
            *(uint2*)(wp + uo) = hi.u;
            *(uint2*)(wp + 512 + uo) = lo.u;
        }
    };

    ISSUE(0); WRITE(0); __syncthreads();

    for (int j = 0; j < T; ++j) {
        const int buf = j & 1;
        if (j + 1 < T) ISSUE(j + 1);
        f32x4 aH[4][2], aL[4][2];
#pragma unroll
        for (int tt = 0; tt < 4; ++tt)
#pragma unroll
            for (int cc = 0; cc < 2; ++cc) {
                aH[tt][cc] = (f32x4){0,0,0,0};
                aL[tt][cc] = (f32x4){0,0,0,0};
            }
        const char* rb = (const char*)&A[buf][c15][0];
#pragma unroll
        for (int ch = 0; ch < 8; ++ch) {
            f16x8 v0h = *(const f16x8*)(p0h + ch*32);
            f16x8 v1h = *(const f16x8*)(p1h + ch*32);
            f16x8 v0l = *(const f16x8*)(p0l + ch*32);
            f16x8 v1l = *(const f16x8*)(p1l + ch*32);
            const int u = (((qq + ch*4) ^ (c15 & 7)) << 4);
#pragma unroll
            for (int tt = 0; tt < 4; ++tt) {
                f16x8 bh = *(const f16x8*)(rb + tt*16384 + u);
                f16x8 bl = *(const f16x8*)(rb + tt*16384 + 512 + u);
                aH[tt][0] = MFMA16(v0h, bh, aH[tt][0]);
                aL[tt][0] = MFMA16(v0h, bl, aL[tt][0]);
                aL[tt][0] = MFMA16(v0l, bh, aL[tt][0]);
                aH[tt][1] = MFMA16(v1h, bh, aH[tt][1]);
                aL[tt][1] = MFMA16(v1h, bl, aL[tt][1]);
                aL[tt][1] = MFMA16(v1l, bh, aL[tt][1]);
            }
        }
#pragma unroll
        for (int tt = 0; tt < 4; ++tt) {
            const int node = base + (t0 + j)*64 + tt*16 + c15;
            const bool nv = node < cend;
#pragma unroll
            for (int cc = 0; cc < 2; ++cc) {
                const int d0 = wv*32 + cc*16 + qq*4;
                if (FM == 0) {
                    if (nv) {
                        F4 bf; bf.v = *(const float4*)(b_f + d0);
                        F4 o;
#pragma unroll
                        for (int e = 0; e < 4; ++e)
                            o.f[e] = aH[tt][cc][e] + aL[tt][cc][e]*INV + bf.f[e];
                        *(float4*)(outW + (size_t)node*256 + d0) = o.v;
                    }
                } else {
                    const int par = (node - 1) >> 3;
                    F4 xf4, c4, q;
                    xf4.v = (float4){0,0,0,0}; c4.v = xf4.v;
                    if (nv) {
                        xf4.v = *(const float4*)(xfR + (size_t)par*256 + d0);
                        c4.v  = *(const float4*)(cR + (size_t)node*256 + d0);
                    }
#pragma unroll
                    for (int e = 0; e < 4; ++e) {
                        float f = fsig(aH[tt][cc][e] + aL[tt][cc][e]*INV + xf4.f[e]);
                        q.f[e] = nv ? f * c4.f[e] : 0.f;
                    }
#pragma unroll
                    for (int e = 0; e < 4; ++e) {
                        q.f[e] += __shfl_xor(q.f[e], 1);
                        q.f[e] += __shfl_xor(q.f[e], 2);
                        q.f[e] += __shfl_xor(q.f[e], 4);
                    }
                    if (((c15 & 7) == 0) && nv)
                        *(float4*)(outW + (size_t)(par - pp)*256 + d0) = q.v;
                }
            }
        }
        if (j + 1 < T) WRITE(buf ^ 1);
        __syncthreads();
    }
}

// ---------------------------------------------------------------------------

extern "C" void kernel_launch(void* const* d_in, const int* in_sizes, int n_in,
                              void* d_out, int out_size, void* d_ws, size_t ws_size,
                              hipStream_t stream)
{
    const float* x     = (const float*)d_in[0];
    const float* W_iou = (const float*)d_in[1];
    const float* U_iou = (const float*)d_in[2];
    const float* b_iou = (const float*)d_in[3];
    const float* W_f   = (const float*)d_in[4];
    const float* U_f   = (const float*)d_in[5];
    const float* b_f   = (const float*)d_in[6];

    float* h = (float*)d_out;

    char* p = (char*)d_ws;
    float* c  = (float*)p;  p += (size_t)NN*256*4;
    float* fc = (float*)p;  p += (size_t)20320*256*4;
    float* ht = (float*)p;  p += (size_t)20320*256*4;
    float* xf = (float*)p;  p += (size_t)NINT*256*4;
    f16* wfh = (f16*)p;  p += 65536*2;
    f16* wfl = (f16*)p;  p += 65536*2;
    f16* ufh = (f16*)p;  p += 65536*2;
    f16* ufl = (f16*)p;  p += 65536*2;
    f16* wih = (f16*)p;  p += 196608*2;
    f16* wil = (f16*)p;  p += 196608*2;
    f16* uih = (f16*)p;  p += 196608*2;
    f16* uil = (f16*)p;  p += 196608*2;

    split_w_kernel<<<256, 256, 0, stream>>>(W_f,   wfh, wfl, 256);
    split_w_kernel<<<256, 256, 0, stream>>>(U_f,   ufh, ufl, 256);
    split_w_kernel<<<768, 256, 0, stream>>>(W_iou, wih, wil, 768);
    split_w_kernel<<<768, 256, 0, stream>>>(U_iou, uih, uil, 768);

    const int S_[8] = {0, 1, 9, 73, 585, 4681, 37449, 200000};
    auto cdiv = [](int a, int b){ return (a + b - 1) / b; };
    auto nchf = [](int T, int cap){ int n = T/4; if (n < 1) n = 1; if (n > cap) n = cap; return n; };

    // all childless nodes: full LSTM with fc = 0. base 24992 (64-aligned tail
    // at 25000 boundary); nodes 24992..24999 recomputed by level-5 parent pass.
    {
        int T = cdiv(NN - 24992, 64);
        int nch = nchf(T, 256);
        iou_ls<1><<<2*nch, 512, 0, stream>>>(x, nullptr, wih, wil, uih, uil,
            b_iou, nullptr, c, h, 24992, NN, T, nch);
    }
    // xf = x @ W_f + b_f for internal nodes
    {
        int T = cdiv(NINT, 64);
        int nch = nchf(T, 512);
        f_ls<0><<<nch, 512, 0, stream>>>(x, wfh, wfl, b_f,
            nullptr, nullptr, xf, 0, NINT, 0, T, nch);
    }
    // levels 5..0: child fc pass + ht segment-sum, then internal-parent LSTM
    for (int l = 5; l >= 0; --l) {
        int ps = S_[l];
        int pe = (S_[l+1] < NINT) ? S_[l+1] : NINT;
        int cs = S_[l+1], ce = S_[l+2];

        int Tc = cdiv(ce - cs, 64);
        int nchc = nchf(Tc, 512);
        f_ls<1><<<nchc, 512, 0, stream>>>(h, ufh, ufl, nullptr,
            xf, c, fc, cs, ce, ps, Tc, nchc);

        ht_sum<<<cdiv((pe - ps)*64, 256), 256, 0, stream>>>(h, ht, ps, pe);

        int Tp = cdiv(pe - ps, 64);
        int nchp = nchf(Tp, 256);
        iou_ls<2><<<2*nchp, 512, 0, stream>>>(x, ht, wih, wil, uih, uil,
            b_iou, fc, c, h, ps, pe, Tp, nchp);
    }
}